// Round 10
// baseline (2992.764 us; speedup 1.0000x reference)
//
#include <hip/hip_runtime.h>
#include <hip/hip_bf16.h>
#include <cstdint>
#include <cstddef>

#define B_    32
#define S_    512
#define IN_   256
#define HID_  512
#define NGATE 1024
#define OUT_  256
#define NWGD  16         // worker WGs per direction (each owns 32 r/u/cand cols)
#define STW   264        // half-stage row stride (256 + 8): 2-way bank slots for b128

typedef float f32x4 __attribute__((ext_vector_type(4)));
typedef short bf16x8 __attribute__((ext_vector_type(8)));
typedef unsigned long long ull;

__device__ inline unsigned short f2bf(float f) {
  return __builtin_bit_cast(unsigned short, __float2bfloat16(f));
}
__device__ inline float bf2f(unsigned short u) {
  union { float f; unsigned int i; } v; v.i = ((unsigned int)u) << 16; return v.f;
}

// ---- cache-controlled stores -------------------------------------------
// slow mode (any placement): sc0 sc1 write-through to IF$ (device coherent
// point).  Baseline-proven.
// fast mode (all 16 WGs of a direction runtime-verified on ONE XCD; R2/R3/
// R4/R7/R9-proven correct): sc0 only — store lands in the XCD's shared L2
// and consumer loads (post-buffer_inv / first-touch) read it there.
__device__ inline void store_short_cc(unsigned short* p, unsigned short val, bool fast) {
  unsigned v = val;
  if (fast) asm volatile("global_store_short %0, %1, off sc0"     :: "v"(p), "v"(v) : "memory");
  else      asm volatile("global_store_short %0, %1, off sc0 sc1" :: "v"(p), "v"(v) : "memory");
}
__device__ inline void store_dword_wt(unsigned* p, unsigned val) {
  asm volatile("global_store_dword %0, %1, off sc0 sc1" :: "v"(p), "v"(val) : "memory");
}
__device__ inline void store_dword_l2(unsigned* p, unsigned val) {
  asm volatile("global_store_dword %0, %1, off sc0" :: "v"(p), "v"(val) : "memory");
}

// ---------------------------------------------------------------- prep ----
__global__ void prep_kernel(const float* __restrict__ x,
                            const float* __restrict__ fcw,
                            unsigned short* __restrict__ Xbf,
                            unsigned short* __restrict__ HFW,
                            unsigned short* __restrict__ HBW,
                            float* __restrict__ pool,
                            unsigned* __restrict__ sync,
                            unsigned short* __restrict__ fcwf)
{
  const int nthreads = gridDim.x * blockDim.x;
  const int gtid = blockIdx.x * blockDim.x + threadIdx.x;

  // x [B,S,IN] -> Xbf [S][B][IN] bf16
  for (int i = gtid; i < S_*B_*IN_; i += nthreads) {
    int c = i & (IN_-1);
    int rem = i >> 8;
    int b = rem & (B_-1);
    int s = rem >> 5;
    Xbf[((size_t)s*B_ + b)*IN_ + c] = f2bf(x[((size_t)b*S_ + s)*IN_ + c]);
  }
  // HFW[0] = 0 (h_{-1}), HBW[S-1] = 0 (hb_S)
  for (int i = gtid; i < B_*HID_; i += nthreads) {
    HFW[i] = 0;
    HBW[(size_t)(S_-1)*B_*HID_ + i] = 0;
  }
  for (int i = gtid; i < B_*HID_; i += nthreads) pool[i] = 0.f;
  for (int i = gtid; i < 4096;    i += nthreads) sync[i] = 0u;
  // fc_w [1280][512] -> fragment order [kc=40][nt=32][lane=64][8]
  for (int i = gtid; i < 40*32*64*8; i += nthreads) {
    int j     = i & 7;
    int lane_ = (i >> 3) & 63;
    int nt    = (i >> 9) & 31;
    int kc    = i >> 14;
    int k = kc*32 + (lane_ >> 4)*8 + j;
    int n = nt*16 + (lane_ & 15);
    fcwf[i] = f2bf(fcw[(size_t)k*HID_ + n]);
  }
}

// ------------------------------------------------------------- pregemm ----
// GX[dir][t*32+b][1024] = x_{t,b} @ Wg[0:256,:] + bg   (bf16)
// GC[dir][t*32+b][512]  = x_{t,b} @ Wc[0:256,:] + bc   (bf16)
__global__ __launch_bounds__(256, 1)
void pregemm_kernel(const unsigned short* __restrict__ Xbf,
                    const float* __restrict__ Wg_fw, const float* __restrict__ bg_fw,
                    const float* __restrict__ Wc_fw, const float* __restrict__ bc_fw,
                    const float* __restrict__ Wg_bw, const float* __restrict__ bg_bw,
                    const float* __restrict__ Wc_bw, const float* __restrict__ bc_bw,
                    unsigned short* __restrict__ GX, unsigned short* __restrict__ GC)
{
  __shared__ unsigned short bsm[4*8*64*8];   // 32KB [nt4][kk8][lane][8]
  const int id  = blockIdx.x;                // 0..12287
  const int dir = id >= 6144;
  const int r0  = id - dir*6144;
  const int mtile = r0 / 24;
  const int sec   = r0 % 24;
  const bool isG  = sec < 16;
  const float* W    = dir ? (isG ? Wg_bw : Wc_bw) : (isG ? Wg_fw : Wc_fw);
  const float* bias = dir ? (isG ? bg_bw : bc_bw) : (isG ? bg_fw : bc_fw);
  const int N     = isG ? NGATE : HID_;
  const int nbase = (isG ? sec : sec - 16) * 64;
  unsigned short* out = isG ? (GX + (size_t)dir*16384*NGATE)
                            : (GC + (size_t)dir*16384*HID_);
  const int m0 = mtile * 64;
  const int tid = threadIdx.x, wave = tid >> 6, lane = tid & 63;
  const int quad = lane >> 4, l16 = lane & 15;

  for (int idx = tid; idx < 4*8*64; idx += 256) {
    int lane_ = idx & 63, kk = (idx >> 6) & 7, nt = idx >> 9;
    int n  = nbase + nt*16 + (lane_ & 15);
    int kb = kk*32 + (lane_ >> 4)*8;
    #pragma unroll
    for (int j = 0; j < 8; ++j)
      bsm[((nt*8 + kk)*64 + lane_)*8 + j] = f2bf(W[(size_t)(kb + j)*N + n]);
  }
  __syncthreads();

  f32x4 acc[4];
  #pragma unroll
  for (int nt = 0; nt < 4; ++nt) acc[nt] = (f32x4){0.f,0.f,0.f,0.f};
  #pragma unroll
  for (int kk = 0; kk < 8; ++kk) {
    bf16x8 af = *(const bf16x8*)(Xbf + (size_t)(m0 + wave*16 + l16)*IN_ + quad*8 + kk*32);
    #pragma unroll
    for (int nt = 0; nt < 4; ++nt) {
      bf16x8 bv = *(const bf16x8*)(&bsm[((nt*8 + kk)*64 + lane)*8]);
      acc[nt] = __builtin_amdgcn_mfma_f32_16x16x32_bf16(af, bv, acc[nt], 0, 0, 0);
    }
  }
  #pragma unroll
  for (int nt = 0; nt < 4; ++nt)
    #pragma unroll
    for (int r = 0; r < 4; ++r) {
      int row = m0 + wave*16 + quad*4 + r;
      int col = nbase + nt*16 + l16;
      out[(size_t)row*N + col] = f2bf(acc[nt][r] + bias[col]);
    }
}

// ----------------------------------------------------------- barrier ----
// R7/R9-proven dual-channel flags, now polled in HALVES: flags
// [hf*8, hf*8+8) cover source columns [hf*256, +256) (WG j owns cols
// [j*32,+32)).  8 lanes per flag.  Fast channel: buffer_inv sc0 (local
// CU-L1 invalidate) + plain load -> L2 hit; hot spin (no s_sleep).  Slow
// channel (agent-scope, baseline-proven) ALWAYS posted, checked every
// 32nd spin — any fast-channel surprise degrades to slow latency, never
// a hang (R2 lesson: never poll a bare sc0 load — SE-scope, stale L1).
__device__ inline void wait_half(const unsigned* basef, const unsigned* bases,
                                 unsigned target, bool fast, int hf) {
  const int fi = hf*8 + (threadIdx.x & 7);
  if (fast) {
    const volatile unsigned* pf = basef + fi*16;
    const unsigned* ps = bases + fi*16;
    int it = 0;
    for (;;) {
      asm volatile("buffer_inv sc0" ::: "memory");   // drop CU L1 (local)
      unsigned v = *pf;                              // plain load -> L2 hit
      if (!__any((int)(v < target))) return;
      if ((++it & 31) == 0) {                        // insurance channel
        unsigned w = __hip_atomic_load(ps, __ATOMIC_RELAXED, __HIP_MEMORY_SCOPE_AGENT);
        if (!__any((int)(w < target))) return;
      }
    }
  } else {
    const unsigned* ps = bases + fi*16;
    for (;;) {
      unsigned v = __hip_atomic_load(ps, __ATOMIC_RELAXED, __HIP_MEMORY_SCOPE_AGENT);
      if (!__any((int)(v < target))) return;
      __builtin_amdgcn_s_sleep(1);
    }
  }
}

// --------------------------------------------------------------- gru ----
// Spray launch: 128 blocks; active iff (blockIdx & 7) < 2 -> dir d pinned
// to XCD d (R2/R3/R4/R7/R9-verified; runtime XCC_ID verdict, slow-mode
// fallback correct on any mapping).
// R10 change (vs R9): CHUNKED consumption.  The gate/cand GEMM's K-chunk
// kk needs exactly source cols [kk*32,+32) = WG kk's output, so each
// phase waits/stages/computes in TWO halves (flags 0-7 then 8-15).  The
// early half is processed while late producers finish -> hides fan-in
// skew (the ~1.5us/step unexplained by the serial-chain arithmetic) and
// overlaps stage-L2 latency with MFMA.  st_lds = 2 half-buffers [32][264].
__global__ __launch_bounds__(512, 1)
void gru_kernel(const float* __restrict__ Wg_fw, const float* __restrict__ Wc_fw,
                const float* __restrict__ Wg_bw, const float* __restrict__ Wc_bw,
                const unsigned short* __restrict__ GX, const unsigned short* __restrict__ GC,
                unsigned short* __restrict__ HFW, unsigned short* __restrict__ HBW,
                unsigned short* __restrict__ RH, unsigned* __restrict__ sync)
{
  __shared__ __align__(16) unsigned short wg_lds[4][16][512];  // 64KB gate B-frags
  __shared__ __align__(16) unsigned short wc_lds[2][16][512];  // 32KB cand B-frags
  __shared__ __align__(16) unsigned short st_lds[2][32][STW];  // 33.8KB half stages
  __shared__ float u_lds[32][32];                              // 4KB u gate

  const int slot = blockIdx.x & 7;
  if (slot >= 2) return;                    // inactive spray block
  const int dir = slot;
  const int g   = blockIdx.x >> 3;          // 0..15
  const int tid = threadIdx.x;
  const int wave = tid >> 6, lane = tid & 63;
  const int quad = lane >> 4, l16 = lane & 15;

  const float* Wg = dir ? Wg_bw : Wg_fw;
  const float* Wc = dir ? Wc_bw : Wc_fw;
  unsigned short* H = dir ? HBW : HFW;                 // [S][B][HID]
  unsigned short* RHd = RH + (size_t)dir*S_*B_*HID_;   // [S][B][HID]
  const unsigned short* GXd = GX + (size_t)dir*16384*NGATE;
  const unsigned short* GCd = GC + (size_t)dir*16384*HID_;
  // flag layout (dwords, all zeroed by prep): per dir 1024-dword block
  unsigned* fAf = sync + dir*1024;            // fast A flags (16 x 16-dw)
  unsigned* fBf = sync + dir*1024 + 256;      // fast B flags
  unsigned* fAs = sync + dir*1024 + 512;      // slow A flags
  unsigned* fBs = sync + dir*1024 + 768;      // slow B flags

  // ---- publish own XCD id (device scope; area zeroed by prep) ----
  {
    // s_getreg_b32 simm16 = size-1[15:11] | offset[10:6] | id[5:0]; XCC_ID=20
    unsigned xcc = __builtin_amdgcn_s_getreg((31 << 11) | (0 << 6) | 20);
    if (tid == 0) store_dword_wt(sync + 2048 + dir*64 + g*4, 0x100u | (xcc & 0xFu));
  }

  // ---- stage weight h-rows (256..767) into LDS as B-fragments ----
  for (int idx = tid; idx < 4*16*64; idx += 512) {
    int lane_ = idx & 63, kk = (idx >> 6) & 15, nt = idx >> 10;
    int l16_ = lane_ & 15;
    int n = (nt < 2) ? (g*32 + nt*16 + l16_) : (512 + g*32 + (nt-2)*16 + l16_);
    int kb = IN_ + kk*32 + (lane_ >> 4)*8;
    #pragma unroll
    for (int j = 0; j < 8; ++j)
      wg_lds[nt][kk][lane_*8 + j] = f2bf(Wg[(size_t)(kb + j)*NGATE + n]);
  }
  for (int idx = tid; idx < 2*16*64; idx += 512) {
    int lane_ = idx & 63, kk = (idx >> 6) & 15, nt = idx >> 10;
    int n  = g*32 + nt*16 + (lane_ & 15);
    int kb = IN_ + kk*32 + (lane_ >> 4)*8;
    #pragma unroll
    for (int j = 0; j < 8; ++j)
      wc_lds[nt][kk][lane_*8 + j] = f2bf(Wc[(size_t)(kb + j)*HID_ + n]);
  }
  __syncthreads();

  // ---- gather all 16 XCD ids of this direction -> uniform verdict ----
  bool fast;
  {
    const unsigned* p = sync + 2048 + dir*64 + (tid & 15)*4;
    unsigned v;
    for (;;) {
      v = __hip_atomic_load(p, __ATOMIC_RELAXED, __HIP_MEMORY_SCOPE_AGENT);
      if (!__any((int)((v & 0x100u) == 0u))) break;
      __builtin_amdgcn_s_sleep(1);
    }
    unsigned v0 = __shfl(v, 0, 64);         // lane0 holds slot 0's id
    fast = (__all((int)(v == v0)) != 0);    // all 16 WGs on one XCD?
  }

  const int amt = wave >> 2, ant = wave & 3;          // phase A: 2mt x 4nt
  const int b0A = amt*16 + quad*4;
  const int bmt = wave & 1, bnt = (wave >> 1) & 1;    // phase B tiles (waves 0-3)
  const int b0B = bmt*16 + quad*4;
  const int colB = g*32 + bnt*16 + l16;
  const int colg = (ant < 2) ? (g*32 + ant*16 + l16)
                             : (512 + g*32 + (ant-2)*16 + l16);
  const int ghalf = g >> 3;                 // which half holds this WG's cols
  const int clA = (g*32 + ((ant < 2) ? ant : 0)*16 + l16) & 255;  // hpA local col
  const int clB = colB & 255;               // hpB local col

  for (int si = 0; si < S_; ++si) {
    const int t  = dir ? (S_-1-si) : si;
    const int to = dir ? (t-1)     : (t+1);
    const unsigned short* Hsrc  = H   + (size_t)t*B_*HID_;
    const unsigned short* RHsrc = RHd + (size_t)t*B_*HID_;

    // ---- prefetch h-independent operands BEFORE the flag waits ----
    unsigned short gx_s[4], gc_s[4];
    {
      const unsigned short* gx = GXd + (size_t)t*B_*NGATE;
      #pragma unroll
      for (int r = 0; r < 4; ++r) gx_s[r] = gx[(size_t)(b0A + r)*NGATE + colg];
      if (wave < 4) {
        #pragma unroll
        for (int r = 0; r < 4; ++r)
          gc_s[r] = GCd[((size_t)t*B_ + b0B + r)*HID_ + colB];
      }
    }

    // ======== phase A: gates = sigmoid(h_prev @ Wg_h + GX[t]) ========
    float hpA[4], hpB[4], gcv[4];
    f32x4 a0 = {0.f,0.f,0.f,0.f}, a1 = {0.f,0.f,0.f,0.f};
    #pragma unroll
    for (int hf = 0; hf < 2; ++hf) {
      wait_half(fBf, fBs, (unsigned)si, fast, hf);   // producers hf*8..+8
      {                                    // stage 32x256 half (16KB)
        const uint4* src = (const uint4*)Hsrc;
        #pragma unroll
        for (int i = 0; i < 2; ++i) {
          int c = tid + i*512;             // 1024 16B chunks
          int row = c >> 5, c16 = c & 31;
          *(uint4*)&st_lds[hf][row][c16*8] = src[row*64 + hf*32 + c16];
        }
      }
      __syncthreads();                     // half staged
      if (hf == ghalf) {                   // own-column scalars live here
        if (ant < 2) {
          #pragma unroll
          for (int r = 0; r < 4; ++r) hpA[r] = bf2f(st_lds[hf][b0A + r][clA]);
        }
        if (wave < 4) {
          #pragma unroll
          for (int r = 0; r < 4; ++r) hpB[r] = bf2f(st_lds[hf][b0B + r][clB]);
        }
      }
      #pragma unroll
      for (int kkl = 0; kkl < 8; ++kkl) {
        bf16x8 af = *(const bf16x8*)(&st_lds[hf][amt*16 + l16][quad*8 + kkl*32]);
        bf16x8 bv = *(const bf16x8*)(&wg_lds[ant][hf*8 + kkl][lane*8]);
        if (kkl & 1) a1 = __builtin_amdgcn_mfma_f32_16x16x32_bf16(af, bv, a1, 0, 0, 0);
        else         a0 = __builtin_amdgcn_mfma_f32_16x16x32_bf16(af, bv, a0, 0, 0, 0);
      }
    }
    {
      f32x4 acc = a0 + a1;
      if (ant < 2) {                        // r -> r*h direct stores
        #pragma unroll
        for (int r = 0; r < 4; ++r) {
          float rv = 1.f / (1.f + __expf(-(acc[r] + bf2f(gx_s[r]))));
          store_short_cc(&RHd[(size_t)t*B_*HID_ + (size_t)(b0A + r)*HID_ + colg],
                         f2bf(rv * hpA[r]), fast);
        }
      } else {                              // u -> LDS (WG-local)
        #pragma unroll
        for (int r = 0; r < 4; ++r)
          u_lds[b0A + r][(ant-2)*16 + l16] = 1.f / (1.f + __expf(-(acc[r] + bf2f(gx_s[r]))));
      }
    }
    __syncthreads();                        // drain rh stores + publish u_lds
    if (tid == 0) {
      if (fast) store_dword_l2(fAf + g*16, (unsigned)(si + 1));
      store_dword_wt(fAs + g*16, (unsigned)(si + 1));
    }

    // ======== phase B: c = tanh(rh @ Wc_h + GC); h update ========
    f32x4 c0 = {0.f,0.f,0.f,0.f}, c1 = {0.f,0.f,0.f,0.f};
    #pragma unroll
    for (int hf = 0; hf < 2; ++hf) {
      wait_half(fAf, fAs, (unsigned)(si + 1), fast, hf);
      {
        const uint4* src = (const uint4*)RHsrc;
        #pragma unroll
        for (int i = 0; i < 2; ++i) {
          int c = tid + i*512;
          int row = c >> 5, c16 = c & 31;
          *(uint4*)&st_lds[hf][row][c16*8] = src[row*64 + hf*32 + c16];
        }
      }
      __syncthreads();                     // half staged
      if (wave < 4) {
        #pragma unroll
        for (int kkl = 0; kkl < 8; ++kkl) {
          bf16x8 af = *(const bf16x8*)(&st_lds[hf][bmt*16 + l16][quad*8 + kkl*32]);
          bf16x8 bv = *(const bf16x8*)(&wc_lds[bnt][hf*8 + kkl][lane*8]);
          if (kkl & 1) c1 = __builtin_amdgcn_mfma_f32_16x16x32_bf16(af, bv, c1, 0, 0, 0);
          else         c0 = __builtin_amdgcn_mfma_f32_16x16x32_bf16(af, bv, c0, 0, 0, 0);
        }
      }
    }
    if (wave < 4 && to >= 0 && to < S_) {
      f32x4 acc = c0 + c1;
      #pragma unroll
      for (int r = 0; r < 4; ++r) {
        float c  = tanhf(acc[r] + bf2f(gc_s[r]));
        float u  = u_lds[b0B + r][bnt*16 + l16];
        float hn = u * hpB[r] + (1.f - u)*c;
        store_short_cc(&H[((size_t)to*B_ + b0B + r)*HID_ + colB], f2bf(hn), fast);
      }
    }
    __syncthreads();                        // drain h stores (all 8 waves)
    if (tid == 0) {
      if (fast) store_dword_l2(fBf + g*16, (unsigned)(si + 1));
      store_dword_wt(fBs + g*16, (unsigned)(si + 1));
    }
  }
}

// ---------------------------------------------------------------- fc ----
// last[b][t] = [HFW[t] | Xbf[t] | HBW[t]]; pool = max_t relu(last@fcw+fcb)
__global__ __launch_bounds__(512, 1)
void fc_kernel(const unsigned short* __restrict__ HFW, const unsigned short* __restrict__ HBW,
               const unsigned short* __restrict__ Xbf,
               const unsigned short* __restrict__ fcwf, const float* __restrict__ fcb,
               float* __restrict__ pool)
{
  __shared__ unsigned short bsm[32*512];   // 32KB weight chunk (frag order)
  __shared__ float red[8*512];             // 16KB cross-wave max reduce
  const int wg = blockIdx.x;               // 128 WGs: b = wg/4, t-quarter = wg%4
  const int b  = wg >> 2;
  const int tid = threadIdx.x, wave = tid >> 6, lane = tid & 63;
  const int quad = lane >> 4, l16 = lane & 15;
  const int t = (wg & 3)*128 + wave*16 + l16;  // A-operand row = t

  f32x4 acc[32];
  #pragma unroll
  for (int nt = 0; nt < 32; ++nt) acc[nt] = (f32x4){0.f,0.f,0.f,0.f};

  for (int kc = 0; kc < 40; ++kc) {
    __syncthreads();
    const uint4* src = (const uint4*)(fcwf + (size_t)kc*32*512);
    uint4* dst = (uint4*)bsm;
    #pragma unroll
    for (int r = 0; r < 4; ++r) dst[tid + r*512] = src[tid + r*512];
    __syncthreads();

    const unsigned short* ap;
    if (kc < 16)      ap = HFW + ((size_t)t*B_ + b)*HID_ + kc*32 + quad*8;        // c_left
    else if (kc < 24) ap = Xbf + ((size_t)t*B_ + b)*IN_ + (kc - 16)*32 + quad*8;  // x
    else              ap = HBW + ((size_t)t*B_ + b)*HID_ + (kc - 24)*32 + quad*8; // c_right
    const bf16x8 af = *(const bf16x8*)ap;
    #pragma unroll
    for (int nt = 0; nt < 32; ++nt) {
      bf16x8 bfv = *(const bf16x8*)(&bsm[(nt*64 + lane)*8]);
      acc[nt] = __builtin_amdgcn_mfma_f32_16x16x32_bf16(af, bfv, acc[nt], 0, 0, 0);
    }
  }
  #pragma unroll
  for (int nt = 0; nt < 32; ++nt) {
    float m = fmaxf(fmaxf(acc[nt][0], acc[nt][1]), fmaxf(acc[nt][2], acc[nt][3]));
    m = fmaxf(m, __shfl_xor(m, 16, 64));
    m = fmaxf(m, __shfl_xor(m, 32, 64));
    if (quad == 0) red[wave*512 + nt*16 + l16] = m;
  }
  __syncthreads();
  {
    float m = red[tid];
    #pragma unroll
    for (int w = 1; w < 8; ++w) m = fmaxf(m, red[w*512 + tid]);
    m = fmaxf(m + fcb[tid], 0.f);
    atomicMax((int*)&pool[(size_t)b*HID_ + tid], __float_as_int(m));
  }
}

// --------------------------------------------------------------- mlp ----
__global__ void mlp_kernel(const float* __restrict__ pool, const float* __restrict__ w,
                           const float* __restrict__ bias, float* __restrict__ out)
{
  __shared__ float p[HID_];
  const int b = blockIdx.x, tid = threadIdx.x;  // 256 threads
  p[tid]       = pool[(size_t)b*HID_ + tid];
  p[tid + 256] = pool[(size_t)b*HID_ + 256 + tid];
  __syncthreads();
  float acc = bias[tid];
  for (int k = 0; k < HID_; ++k) acc += p[k] * w[(size_t)k*OUT_ + tid];
  out[(size_t)b*OUT_ + tid] = acc;
}

// ------------------------------------------------------------ launch ----
extern "C" void kernel_launch(void* const* d_in, const int* in_sizes, int n_in,
                              void* d_out, int out_size, void* d_ws, size_t ws_size,
                              hipStream_t stream)
{
  const float* x    = (const float*)d_in[0];
  const float* fwWg = (const float*)d_in[1];
  const float* fwbg = (const float*)d_in[2];
  const float* fwWc = (const float*)d_in[3];
  const float* fwbc = (const float*)d_in[4];
  const float* bwWg = (const float*)d_in[5];
  const float* bwbg = (const float*)d_in[6];
  const float* bwWc = (const float*)d_in[7];
  const float* bwbc = (const float*)d_in[8];
  const float* fcw  = (const float*)d_in[9];
  const float* fcb  = (const float*)d_in[10];
  const float* mlpw = (const float*)d_in[11];
  const float* mlpb = (const float*)d_in[12];
  float* out = (float*)d_out;

  char* p = (char*)d_ws;
  auto take = [&](size_t bytes) { char* r = p; p += (bytes + 255) & ~size_t(255); return r; };
  unsigned short* Xbf  = (unsigned short*)take((size_t)S_*B_*IN_*2);          // 8MB
  unsigned short* HFW  = (unsigned short*)take((size_t)S_*B_*HID_*2);         // 16.8MB
  unsigned short* HBW  = (unsigned short*)take((size_t)S_*B_*HID_*2);         // 16.8MB
  unsigned short* GX   = (unsigned short*)take((size_t)2*S_*B_*NGATE*2);      // 67MB
  unsigned short* GC   = (unsigned short*)take((size_t)2*S_*B_*HID_*2);       // 33.6MB
  unsigned short* RH   = (unsigned short*)take((size_t)2*S_*B_*HID_*2);       // 33.6MB
  unsigned short* fcwf = (unsigned short*)take((size_t)40*32*64*8*2);         // 1.25MB
  float*          pool = (float*)take((size_t)B_*HID_*4);
  unsigned*       sync = (unsigned*)take(16384);

  prep_kernel<<<2048, 256, 0, stream>>>(x, fcw, Xbf, HFW, HBW, pool, sync, fcwf);
  pregemm_kernel<<<12288, 256, 0, stream>>>(Xbf, fwWg, fwbg, fwWc, fwbc,
                                            bwWg, bwbg, bwWc, bwbc, GX, GC);
  // spray launch: 128 blocks, active = blockIdx%8 in {0,1}  -> one XCD/dir
  gru_kernel<<<128, 512, 0, stream>>>(fwWg, fwWc, bwWg, bwWc,
                                      GX, GC, HFW, HBW, RH, sync);
  fc_kernel<<<128, 512, 0, stream>>>(HFW, HBW, Xbf, fcwf, fcb, pool);
  mlp_kernel<<<32, 256, 0, stream>>>(pool, mlpw, mlpb, out);
}

// Round 11
// 2396.332 us; speedup vs baseline: 1.2489x; 1.2489x over previous
//
#include <hip/hip_runtime.h>
#include <hip/hip_bf16.h>
#include <cstdint>
#include <cstddef>

#define B_    32
#define S_    512
#define IN_   256
#define HID_  512
#define NGATE 1024
#define OUT_  256
#define NWGD  16         // worker WGs per direction (each owns 32 r/u/cand cols)
#define STP   536        // LDS stage row stride (R9-proven)

typedef float f32x4 __attribute__((ext_vector_type(4)));
typedef short bf16x8 __attribute__((ext_vector_type(8)));
typedef unsigned long long ull;

__device__ inline unsigned short f2bf(float f) {
  return __builtin_bit_cast(unsigned short, __float2bfloat16(f));
}
__device__ inline float bf2f(unsigned short u) {
  union { float f; unsigned int i; } v; v.i = ((unsigned int)u) << 16; return v.f;
}

// ---- cache-controlled stores (R9-proven) -------------------------------
__device__ inline void store_short_cc(unsigned short* p, unsigned short val, bool fast) {
  unsigned v = val;
  if (fast) asm volatile("global_store_short %0, %1, off sc0"     :: "v"(p), "v"(v) : "memory");
  else      asm volatile("global_store_short %0, %1, off sc0 sc1" :: "v"(p), "v"(v) : "memory");
}
__device__ inline void store_dword_wt(unsigned* p, unsigned val) {
  asm volatile("global_store_dword %0, %1, off sc0 sc1" :: "v"(p), "v"(val) : "memory");
}
__device__ inline void store_dword_l2(unsigned* p, unsigned val) {
  asm volatile("global_store_dword %0, %1, off sc0" :: "v"(p), "v"(val) : "memory");
}

// ---------------------------------------------------------------- prep ----
__global__ void prep_kernel(const float* __restrict__ x,
                            const float* __restrict__ fcw,
                            unsigned short* __restrict__ Xbf,
                            unsigned short* __restrict__ HFW,
                            unsigned short* __restrict__ HBW,
                            float* __restrict__ pool,
                            unsigned* __restrict__ sync,
                            unsigned short* __restrict__ fcwf)
{
  const int nthreads = gridDim.x * blockDim.x;
  const int gtid = blockIdx.x * blockDim.x + threadIdx.x;

  // x [B,S,IN] -> Xbf [S][B][IN] bf16
  for (int i = gtid; i < S_*B_*IN_; i += nthreads) {
    int c = i & (IN_-1);
    int rem = i >> 8;
    int b = rem & (B_-1);
    int s = rem >> 5;
    Xbf[((size_t)s*B_ + b)*IN_ + c] = f2bf(x[((size_t)b*S_ + s)*IN_ + c]);
  }
  // HFW[0] = 0 (h_{-1}), HBW[S-1] = 0 (hb_S)
  for (int i = gtid; i < B_*HID_; i += nthreads) {
    HFW[i] = 0;
    HBW[(size_t)(S_-1)*B_*HID_ + i] = 0;
  }
  for (int i = gtid; i < B_*HID_; i += nthreads) pool[i] = 0.f;
  for (int i = gtid; i < 4096;    i += nthreads) sync[i] = 0u;
  // fc_w [1280][512] -> fragment order [kc=40][nt=32][lane=64][8]
  for (int i = gtid; i < 40*32*64*8; i += nthreads) {
    int j     = i & 7;
    int lane_ = (i >> 3) & 63;
    int nt    = (i >> 9) & 31;
    int kc    = i >> 14;
    int k = kc*32 + (lane_ >> 4)*8 + j;
    int n = nt*16 + (lane_ & 15);
    fcwf[i] = f2bf(fcw[(size_t)k*HID_ + n]);
  }
}

// ------------------------------------------------------------- pregemm ----
// GX[dir][t*32+b][1024] = x_{t,b} @ Wg[0:256,:] + bg   (bf16)
// GC[dir][t*32+b][512]  = x_{t,b} @ Wc[0:256,:] + bc   (bf16)
__global__ __launch_bounds__(256, 1)
void pregemm_kernel(const unsigned short* __restrict__ Xbf,
                    const float* __restrict__ Wg_fw, const float* __restrict__ bg_fw,
                    const float* __restrict__ Wc_fw, const float* __restrict__ bc_fw,
                    const float* __restrict__ Wg_bw, const float* __restrict__ bg_bw,
                    const float* __restrict__ Wc_bw, const float* __restrict__ bc_bw,
                    unsigned short* __restrict__ GX, unsigned short* __restrict__ GC)
{
  __shared__ unsigned short bsm[4*8*64*8];   // 32KB [nt4][kk8][lane][8]
  const int id  = blockIdx.x;                // 0..12287
  const int dir = id >= 6144;
  const int r0  = id - dir*6144;
  const int mtile = r0 / 24;
  const int sec   = r0 % 24;
  const bool isG  = sec < 16;
  const float* W    = dir ? (isG ? Wg_bw : Wc_bw) : (isG ? Wg_fw : Wc_fw);
  const float* bias = dir ? (isG ? bg_bw : bc_bw) : (isG ? bg_fw : bc_fw);
  const int N     = isG ? NGATE : HID_;
  const int nbase = (isG ? sec : sec - 16) * 64;
  unsigned short* out = isG ? (GX + (size_t)dir*16384*NGATE)
                            : (GC + (size_t)dir*16384*HID_);
  const int m0 = mtile * 64;
  const int tid = threadIdx.x, wave = tid >> 6, lane = tid & 63;
  const int quad = lane >> 4, l16 = lane & 15;

  for (int idx = tid; idx < 4*8*64; idx += 256) {
    int lane_ = idx & 63, kk = (idx >> 6) & 7, nt = idx >> 9;
    int n  = nbase + nt*16 + (lane_ & 15);
    int kb = kk*32 + (lane_ >> 4)*8;
    #pragma unroll
    for (int j = 0; j < 8; ++j)
      bsm[((nt*8 + kk)*64 + lane_)*8 + j] = f2bf(W[(size_t)(kb + j)*N + n]);
  }
  __syncthreads();

  f32x4 acc[4];
  #pragma unroll
  for (int nt = 0; nt < 4; ++nt) acc[nt] = (f32x4){0.f,0.f,0.f,0.f};
  #pragma unroll
  for (int kk = 0; kk < 8; ++kk) {
    bf16x8 af = *(const bf16x8*)(Xbf + (size_t)(m0 + wave*16 + l16)*IN_ + quad*8 + kk*32);
    #pragma unroll
    for (int nt = 0; nt < 4; ++nt) {
      bf16x8 bv = *(const bf16x8*)(&bsm[((nt*8 + kk)*64 + lane)*8]);
      acc[nt] = __builtin_amdgcn_mfma_f32_16x16x32_bf16(af, bv, acc[nt], 0, 0, 0);
    }
  }
  #pragma unroll
  for (int nt = 0; nt < 4; ++nt)
    #pragma unroll
    for (int r = 0; r < 4; ++r) {
      int row = m0 + wave*16 + quad*4 + r;
      int col = nbase + nt*16 + l16;
      out[(size_t)row*N + col] = f2bf(acc[nt][r] + bias[col]);
    }
}

// ----------------------------------------------------------- barrier ----
// R9-proven dual-channel flags, unchanged.  16 per-WG flags, each on its
// own 64B line; lane l polls flag (l&15).  Producer: __syncthreads drains
// data stores (vmcnt(0) before s_barrier), then tid0 posts the flag(s).
// slow channel: post sc0 sc1 (IF$), poll agent-scope relaxed atomics.
// fast channel (same-XCD verified): post sc0 (shared XCD L2); poll =
// buffer_inv sc0 (local CU-L1 invalidate) + plain load -> L2 hit.  Slow
// flag ALWAYS posted; fast waiters check it every 32nd spin (R2 lesson:
// never poll a bare sc0 load — SE-scope, can hit stale L1).
__device__ inline void wait_flags2(const unsigned* basef, const unsigned* bases,
                                   unsigned target, bool fast) {
  const int fi = threadIdx.x & (NWGD-1);
  if (fast) {
    const volatile unsigned* pf = basef + fi*16;
    const unsigned* ps = bases + fi*16;
    int it = 0;
    for (;;) {
      asm volatile("buffer_inv sc0" ::: "memory");   // drop CU L1 (local)
      unsigned v = *pf;                              // plain load -> L2 hit
      if (!__any((int)(v < target))) return;
      if ((++it & 31) == 0) {                        // insurance channel
        unsigned w = __hip_atomic_load(ps, __ATOMIC_RELAXED, __HIP_MEMORY_SCOPE_AGENT);
        if (!__any((int)(w < target))) return;
      }
      __builtin_amdgcn_s_sleep(1);
    }
  } else {
    const unsigned* ps = bases + fi*16;
    for (;;) {
      unsigned v = __hip_atomic_load(ps, __ATOMIC_RELAXED, __HIP_MEMORY_SCOPE_AGENT);
      if (!__any((int)(v < target))) return;
      __builtin_amdgcn_s_sleep(1);
    }
  }
}

// --------------------------------------------------------------- gru ----
// Spray launch: 128 blocks; active iff (blockIdx & 7) < 2 -> dir d pinned
// to XCD d (R2/R3/R4/R7/R9-verified; runtime XCC_ID verdict, slow-mode
// fallback correct on any mapping).  R9's LDS staging kept verbatim.
// R11 change (vs R9): 4 WAVES (256 threads) with unified tile ownership.
// Wave w owns (mt=w&1, col-block=w>>1): in phase A it computes its r-tile
// AND u-tile together (same A-frags, 32 MFMAs) so u stays in REGISTERS
// (u_lds + its publish dependency deleted); hp is read once and reused
// for both rh and the h-update (identical coords).  Phase B: all 4 waves
// compute (R9 idled half the block).  Barriers sync 4 waves not 8 ->
// about half the rendezvous skew (R10 measured ~0.3us per rendezvous).
__global__ __launch_bounds__(256, 1)
void gru_kernel(const float* __restrict__ Wg_fw, const float* __restrict__ Wc_fw,
                const float* __restrict__ Wg_bw, const float* __restrict__ Wc_bw,
                const unsigned short* __restrict__ GX, const unsigned short* __restrict__ GC,
                unsigned short* __restrict__ HFW, unsigned short* __restrict__ HBW,
                unsigned short* __restrict__ RH, unsigned* __restrict__ sync)
{
  __shared__ __align__(16) unsigned short wg_lds[4][16][512];  // 64KB gate B-frags
  __shared__ __align__(16) unsigned short wc_lds[2][16][512];  // 32KB cand B-frags
  __shared__ __align__(16) unsigned short st_lds[32*STP];      // 33.5KB A-tile stage

  const int slot = blockIdx.x & 7;
  if (slot >= 2) return;                    // inactive spray block
  const int dir = slot;
  const int g   = blockIdx.x >> 3;          // 0..15
  const int tid = threadIdx.x;
  const int wave = tid >> 6, lane = tid & 63;
  const int quad = lane >> 4, l16 = lane & 15;

  const float* Wg = dir ? Wg_bw : Wg_fw;
  const float* Wc = dir ? Wc_bw : Wc_fw;
  unsigned short* H = dir ? HBW : HFW;                 // [S][B][HID]
  unsigned short* RHd = RH + (size_t)dir*S_*B_*HID_;   // [S][B][HID]
  const unsigned short* GXd = GX + (size_t)dir*16384*NGATE;
  const unsigned short* GCd = GC + (size_t)dir*16384*HID_;
  // flag layout (dwords, all zeroed by prep): per dir 1024-dword block
  unsigned* fAf = sync + dir*1024;            // fast A flags (16 x 16-dw)
  unsigned* fBf = sync + dir*1024 + 256;      // fast B flags
  unsigned* fAs = sync + dir*1024 + 512;      // slow A flags
  unsigned* fBs = sync + dir*1024 + 768;      // slow B flags

  // ---- publish own XCD id (device scope; area zeroed by prep) ----
  {
    // s_getreg_b32 simm16 = size-1[15:11] | offset[10:6] | id[5:0]; XCC_ID=20
    unsigned xcc = __builtin_amdgcn_s_getreg((31 << 11) | (0 << 6) | 20);
    if (tid == 0) store_dword_wt(sync + 2048 + dir*64 + g*4, 0x100u | (xcc & 0xFu));
  }

  // ---- stage weight h-rows (256..767) into LDS as B-fragments ----
  for (int idx = tid; idx < 4*16*64; idx += 256) {
    int lane_ = idx & 63, kk = (idx >> 6) & 15, nt = idx >> 10;
    int l16_ = lane_ & 15;
    int n = (nt < 2) ? (g*32 + nt*16 + l16_) : (512 + g*32 + (nt-2)*16 + l16_);
    int kb = IN_ + kk*32 + (lane_ >> 4)*8;
    #pragma unroll
    for (int j = 0; j < 8; ++j)
      wg_lds[nt][kk][lane_*8 + j] = f2bf(Wg[(size_t)(kb + j)*NGATE + n]);
  }
  for (int idx = tid; idx < 2*16*64; idx += 256) {
    int lane_ = idx & 63, kk = (idx >> 6) & 15, nt = idx >> 10;
    int n  = g*32 + nt*16 + (lane_ & 15);
    int kb = IN_ + kk*32 + (lane_ >> 4)*8;
    #pragma unroll
    for (int j = 0; j < 8; ++j)
      wc_lds[nt][kk][lane_*8 + j] = f2bf(Wc[(size_t)(kb + j)*HID_ + n]);
  }
  __syncthreads();

  // ---- gather all 16 XCD ids of this direction -> uniform verdict ----
  bool fast;
  {
    const unsigned* p = sync + 2048 + dir*64 + (tid & 15)*4;
    unsigned v;
    for (;;) {
      v = __hip_atomic_load(p, __ATOMIC_RELAXED, __HIP_MEMORY_SCOPE_AGENT);
      if (!__any((int)((v & 0x100u) == 0u))) break;
      __builtin_amdgcn_s_sleep(1);
    }
    unsigned v0 = __shfl(v, 0, 64);         // lane0 holds slot 0's id
    fast = (__all((int)(v == v0)) != 0);    // all 16 WGs on one XCD?
  }

  // tile ownership: wave w -> (mt = w&1, col-block nc = w>>1)
  const int mt = wave & 1, nc = wave >> 1;
  const int b0 = mt*16 + quad*4;            // this lane's 4 output rows
  const int colr = g*32 + nc*16 + l16;      // r-gate col == cand/h col
  const int colu = 512 + colr;              // u-gate col

  for (int si = 0; si < S_; ++si) {
    const int t  = dir ? (S_-1-si) : si;
    const int to = dir ? (t-1)     : (t+1);

    // ---- prefetch h-independent operands BEFORE the flag wait ----
    unsigned short gxr_s[4], gxu_s[4], gc_s[4];
    {
      const unsigned short* gx = GXd + (size_t)t*B_*NGATE;
      #pragma unroll
      for (int r = 0; r < 4; ++r) {
        gxr_s[r] = gx[(size_t)(b0 + r)*NGATE + colr];
        gxu_s[r] = gx[(size_t)(b0 + r)*NGATE + colu];
        gc_s[r]  = GCd[((size_t)t*B_ + b0 + r)*HID_ + colr];
      }
    }

    wait_flags2(fBf, fBs, (unsigned)si, fast);   // h_prev (H[t]) fully posted

    // ---- stage H[t] (32KB, coalesced) into st_lds ----
    {
      const uint4* src = (const uint4*)(H + (size_t)t*B_*HID_);
      #pragma unroll
      for (int i = 0; i < 8; ++i) {
        int c = tid + i*256;                 // 2048 16B chunks
        int row = c >> 6, col8 = c & 63;
        *(uint4*)&st_lds[row*STP + col8*8] = src[c];
      }
    }
    __syncthreads();                        // stage complete

    // ======== phase A: r-tile AND u-tile per wave (u stays in regs) ====
    float hp[4], uv[4];
    {
      #pragma unroll
      for (int r = 0; r < 4; ++r) hp[r] = bf2f(st_lds[(b0 + r)*STP + colr]);
      f32x4 a0 = {0.f,0.f,0.f,0.f}, a1 = {0.f,0.f,0.f,0.f};
      f32x4 u0 = {0.f,0.f,0.f,0.f}, u1 = {0.f,0.f,0.f,0.f};
      #pragma unroll
      for (int kk = 0; kk < 16; ++kk) {
        bf16x8 af  = *(const bf16x8*)(&st_lds[(mt*16 + l16)*STP + quad*8 + kk*32]);
        bf16x8 bvr = *(const bf16x8*)(&wg_lds[nc][kk][lane*8]);
        bf16x8 bvu = *(const bf16x8*)(&wg_lds[2 + nc][kk][lane*8]);
        if (kk & 1) {
          a1 = __builtin_amdgcn_mfma_f32_16x16x32_bf16(af, bvr, a1, 0, 0, 0);
          u1 = __builtin_amdgcn_mfma_f32_16x16x32_bf16(af, bvu, u1, 0, 0, 0);
        } else {
          a0 = __builtin_amdgcn_mfma_f32_16x16x32_bf16(af, bvr, a0, 0, 0, 0);
          u0 = __builtin_amdgcn_mfma_f32_16x16x32_bf16(af, bvu, u0, 0, 0, 0);
        }
      }
      f32x4 racc = a0 + a1, uacc = u0 + u1;
      #pragma unroll
      for (int r = 0; r < 4; ++r) {
        float rv = 1.f / (1.f + __expf(-(racc[r] + bf2f(gxr_s[r]))));
        store_short_cc(&RHd[(size_t)t*B_*HID_ + (size_t)(b0 + r)*HID_ + colr],
                       f2bf(rv * hp[r]), fast);
        uv[r] = 1.f / (1.f + __expf(-(uacc[r] + bf2f(gxu_s[r]))));
      }
    }
    __syncthreads();                        // drain rh stores (all 4 waves)
    if (tid == 0) {
      if (fast) store_dword_l2(fAf + g*16, (unsigned)(si + 1));
      store_dword_wt(fAs + g*16, (unsigned)(si + 1));
    }

    // ======== phase B: all 4 waves; c = tanh(rh @ Wc_h + GC); h update ==
    wait_flags2(fAf, fAs, (unsigned)(si + 1), fast);
    {
      const uint4* src = (const uint4*)(RHd + (size_t)t*B_*HID_);
      #pragma unroll
      for (int i = 0; i < 8; ++i) {
        int c = tid + i*256;
        int row = c >> 6, col8 = c & 63;
        *(uint4*)&st_lds[row*STP + col8*8] = src[c];
      }
    }
    __syncthreads();                        // stage complete

    {
      f32x4 c0 = {0.f,0.f,0.f,0.f}, c1 = {0.f,0.f,0.f,0.f};
      #pragma unroll
      for (int kk = 0; kk < 16; ++kk) {
        bf16x8 af = *(const bf16x8*)(&st_lds[(mt*16 + l16)*STP + quad*8 + kk*32]);
        bf16x8 bv = *(const bf16x8*)(&wc_lds[nc][kk][lane*8]);
        if (kk & 1) c1 = __builtin_amdgcn_mfma_f32_16x16x32_bf16(af, bv, c1, 0, 0, 0);
        else        c0 = __builtin_amdgcn_mfma_f32_16x16x32_bf16(af, bv, c0, 0, 0, 0);
      }
      f32x4 cacc = c0 + c1;
      if (to >= 0 && to < S_) {
        #pragma unroll
        for (int r = 0; r < 4; ++r) {
          float c  = tanhf(cacc[r] + bf2f(gc_s[r]));
          float hn = uv[r] * hp[r] + (1.f - uv[r]) * c;
          store_short_cc(&H[((size_t)to*B_ + b0 + r)*HID_ + colr], f2bf(hn), fast);
        }
      }
    }
    __syncthreads();                        // drain h stores (all 4 waves)
    if (tid == 0) {
      if (fast) store_dword_l2(fBf + g*16, (unsigned)(si + 1));
      store_dword_wt(fBs + g*16, (unsigned)(si + 1));
    }
  }
}

// ---------------------------------------------------------------- fc ----
// last[b][t] = [HFW[t] | Xbf[t] | HBW[t]]; pool = max_t relu(last@fcw+fcb)
__global__ __launch_bounds__(512, 1)
void fc_kernel(const unsigned short* __restrict__ HFW, const unsigned short* __restrict__ HBW,
               const unsigned short* __restrict__ Xbf,
               const unsigned short* __restrict__ fcwf, const float* __restrict__ fcb,
               float* __restrict__ pool)
{
  __shared__ unsigned short bsm[32*512];   // 32KB weight chunk (frag order)
  __shared__ float red[8*512];             // 16KB cross-wave max reduce
  const int wg = blockIdx.x;               // 128 WGs: b = wg/4, t-quarter = wg%4
  const int b  = wg >> 2;
  const int tid = threadIdx.x, wave = tid >> 6, lane = tid & 63;
  const int quad = lane >> 4, l16 = lane & 15;
  const int t = (wg & 3)*128 + wave*16 + l16;  // A-operand row = t

  f32x4 acc[32];
  #pragma unroll
  for (int nt = 0; nt < 32; ++nt) acc[nt] = (f32x4){0.f,0.f,0.f,0.f};

  for (int kc = 0; kc < 40; ++kc) {
    __syncthreads();
    const uint4* src = (const uint4*)(fcwf + (size_t)kc*32*512);
    uint4* dst = (uint4*)bsm;
    #pragma unroll
    for (int r = 0; r < 4; ++r) dst[tid + r*512] = src[tid + r*512];
    __syncthreads();

    const unsigned short* ap;
    if (kc < 16)      ap = HFW + ((size_t)t*B_ + b)*HID_ + kc*32 + quad*8;        // c_left
    else if (kc < 24) ap = Xbf + ((size_t)t*B_ + b)*IN_ + (kc - 16)*32 + quad*8;  // x
    else              ap = HBW + ((size_t)t*B_ + b)*HID_ + (kc - 24)*32 + quad*8; // c_right
    const bf16x8 af = *(const bf16x8*)ap;
    #pragma unroll
    for (int nt = 0; nt < 32; ++nt) {
      bf16x8 bfv = *(const bf16x8*)(&bsm[(nt*64 + lane)*8]);
      acc[nt] = __builtin_amdgcn_mfma_f32_16x16x32_bf16(af, bfv, acc[nt], 0, 0, 0);
    }
  }
  #pragma unroll
  for (int nt = 0; nt < 32; ++nt) {
    float m = fmaxf(fmaxf(acc[nt][0], acc[nt][1]), fmaxf(acc[nt][2], acc[nt][3]));
    m = fmaxf(m, __shfl_xor(m, 16, 64));
    m = fmaxf(m, __shfl_xor(m, 32, 64));
    if (quad == 0) red[wave*512 + nt*16 + l16] = m;
  }
  __syncthreads();
  {
    float m = red[tid];
    #pragma unroll
    for (int w = 1; w < 8; ++w) m = fmaxf(m, red[w*512 + tid]);
    m = fmaxf(m + fcb[tid], 0.f);
    atomicMax((int*)&pool[(size_t)b*HID_ + tid], __float_as_int(m));
  }
}

// --------------------------------------------------------------- mlp ----
__global__ void mlp_kernel(const float* __restrict__ pool, const float* __restrict__ w,
                           const float* __restrict__ bias, float* __restrict__ out)
{
  __shared__ float p[HID_];
  const int b = blockIdx.x, tid = threadIdx.x;  // 256 threads
  p[tid]       = pool[(size_t)b*HID_ + tid];
  p[tid + 256] = pool[(size_t)b*HID_ + 256 + tid];
  __syncthreads();
  float acc = bias[tid];
  for (int k = 0; k < HID_; ++k) acc += p[k] * w[(size_t)k*OUT_ + tid];
  out[(size_t)b*OUT_ + tid] = acc;
}

// ------------------------------------------------------------ launch ----
extern "C" void kernel_launch(void* const* d_in, const int* in_sizes, int n_in,
                              void* d_out, int out_size, void* d_ws, size_t ws_size,
                              hipStream_t stream)
{
  const float* x    = (const float*)d_in[0];
  const float* fwWg = (const float*)d_in[1];
  const float* fwbg = (const float*)d_in[2];
  const float* fwWc = (const float*)d_in[3];
  const float* fwbc = (const float*)d_in[4];
  const float* bwWg = (const float*)d_in[5];
  const float* bwbg = (const float*)d_in[6];
  const float* bwWc = (const float*)d_in[7];
  const float* bwbc = (const float*)d_in[8];
  const float* fcw  = (const float*)d_in[9];
  const float* fcb  = (const float*)d_in[10];
  const float* mlpw = (const float*)d_in[11];
  const float* mlpb = (const float*)d_in[12];
  float* out = (float*)d_out;

  char* p = (char*)d_ws;
  auto take = [&](size_t bytes) { char* r = p; p += (bytes + 255) & ~size_t(255); return r; };
  unsigned short* Xbf  = (unsigned short*)take((size_t)S_*B_*IN_*2);          // 8MB
  unsigned short* HFW  = (unsigned short*)take((size_t)S_*B_*HID_*2);         // 16.8MB
  unsigned short* HBW  = (unsigned short*)take((size_t)S_*B_*HID_*2);         // 16.8MB
  unsigned short* GX   = (unsigned short*)take((size_t)2*S_*B_*NGATE*2);      // 67MB
  unsigned short* GC   = (unsigned short*)take((size_t)2*S_*B_*HID_*2);       // 33.6MB
  unsigned short* RH   = (unsigned short*)take((size_t)2*S_*B_*HID_*2);       // 33.6MB
  unsigned short* fcwf = (unsigned short*)take((size_t)40*32*64*8*2);         // 1.25MB
  float*          pool = (float*)take((size_t)B_*HID_*4);
  unsigned*       sync = (unsigned*)take(16384);

  prep_kernel<<<2048, 256, 0, stream>>>(x, fcw, Xbf, HFW, HBW, pool, sync, fcwf);
  pregemm_kernel<<<12288, 256, 0, stream>>>(Xbf, fwWg, fwbg, fwWc, fwbc,
                                            bwWg, bwbg, bwWc, bwbc, GX, GC);
  // spray launch: 128 blocks, active = blockIdx%8 in {0,1}  -> one XCD/dir
  gru_kernel<<<128, 256, 0, stream>>>(fwWg, fwWc, bwWg, bwWc,
                                      GX, GC, HFW, HBW, RH, sync);
  fc_kernel<<<128, 512, 0, stream>>>(HFW, HBW, Xbf, fcwf, fcb, pool);
  mlp_kernel<<<32, 256, 0, stream>>>(pool, mlpw, mlpb, out);
}